// Round 1
// baseline (367.782 us; speedup 1.0000x reference)
//
#include <hip/hip_runtime.h>
#include <math.h>

// ForwardKinematics: B=524288 elements, J=24 joints, fp32.
// One thread per element; block of 128 threads owns 128 contiguous elements.
// LDS-staged transposed layout for coalesced global access.

#define NB 524288
#define NJ 24
#define BLOCK 128
#define STRIDE 129   // 128 cols + 1 pad -> bank = (row + col) % 32, conflict-free column reads

namespace {
constexpr int PAR[NJ] = {-1,0,0,0,1,2,3,4,5,6,7,8,9,9,9,12,13,14,16,17,18,19,20,21};
}

__global__ __launch_bounds__(BLOCK)
void ForwardKinematics_51342039056994_kernel(
    const float* __restrict__ root_q,   // (B,4)
    const float* __restrict__ root_p,   // (B,3)
    const float* __restrict__ loc_q,    // (B,24,4)
    const float* __restrict__ bones,    // (B,24)
    const float* __restrict__ rest_d,   // (24,3)
    float* __restrict__ out)            // (B,24,3)
{
    __shared__ float lds[96 * STRIDE];  // rows: 4*j+d (quat comp), cols: element-in-block
    __shared__ float rd[NJ * 3];

    const int tid = threadIdx.x;
    const int blockBase = blockIdx.x * BLOCK;
    const int b = blockBase + tid;

    if (tid < NJ * 3) rd[tid] = rest_d[tid];

    // ---- Stage local quats: 128 elems * 96 floats = 3072 float4, coalesced ----
    {
        const float4* src = (const float4*)(loc_q + (size_t)blockBase * 96);
        #pragma unroll
        for (int m = 0; m < 24; ++m) {
            int g = m * BLOCK + tid;      // float4 index within block region [0,3072)
            float4 v = src[g];
            int t = g / 24;               // element column
            int k = 4 * (g % 24);         // row base (joint*4)
            lds[(k + 0) * STRIDE + t] = v.x;
            lds[(k + 1) * STRIDE + t] = v.y;
            lds[(k + 2) * STRIDE + t] = v.z;
            lds[(k + 3) * STRIDE + t] = v.w;
        }
    }

    // ---- Bone lengths: 6 aligned float4 per thread (96B block fully consumed) ----
    float bl[NJ];
    {
        const float4* bsrc = (const float4*)(bones + (size_t)b * NJ);
        #pragma unroll
        for (int m = 0; m < 6; ++m) {
            float4 v = bsrc[m];
            bl[4*m+0] = v.x; bl[4*m+1] = v.y; bl[4*m+2] = v.z; bl[4*m+3] = v.w;
        }
    }

    // ---- Root quat (coalesced float4) and root position (3 dwords) ----
    float4 rq = ((const float4*)root_q)[b];
    float rpx = root_p[b*3+0], rpy = root_p[b*3+1], rpz = root_p[b*3+2];

    __syncthreads();

    // ---- Compute phase: column-local, no barriers needed ----
    float gqw[NJ], gqx[NJ], gqy[NJ], gqz[NJ];
    float gpx[NJ], gpy[NJ], gpz[NJ];

    {
        float inv = 1.0f / (sqrtf(rq.x*rq.x + rq.y*rq.y + rq.z*rq.z + rq.w*rq.w) + 1e-8f);
        gqw[0] = rq.x * inv; gqx[0] = rq.y * inv; gqy[0] = rq.z * inv; gqz[0] = rq.w * inv;
        gpx[0] = rpx; gpy[0] = rpy; gpz[0] = rpz;
        // position of joint 0 -> LDS rows 0..2 (overwrites unused local quat 0)
        lds[0 * STRIDE + tid] = rpx;
        lds[1 * STRIDE + tid] = rpy;
        lds[2 * STRIDE + tid] = rpz;
    }

    #pragma unroll
    for (int j = 1; j < NJ; ++j) {
        const int p = PAR[j];
        // local quat j from LDS (conflict-free column read)
        float lw = lds[(4*j + 0) * STRIDE + tid];
        float lx = lds[(4*j + 1) * STRIDE + tid];
        float ly = lds[(4*j + 2) * STRIDE + tid];
        float lz = lds[(4*j + 3) * STRIDE + tid];
        float invn = 1.0f / (sqrtf(lw*lw + lx*lx + ly*ly + lz*lz) + 1e-8f);
        lw *= invn; lx *= invn; ly *= invn; lz *= invn;

        float pw = gqw[p], pqx = gqx[p], pqy = gqy[p], pqz = gqz[p];

        // glob_q[j] = parent_q * local_q   (dead for leaves -> DCE)
        gqw[j] = pw*lw - pqx*lx - pqy*ly - pqz*lz;
        gqx[j] = pw*lx + pqx*lw + pqy*lz - pqz*ly;
        gqy[j] = pw*ly - pqx*lz + pqy*lw + pqz*lx;
        gqz[j] = pw*lz + pqx*ly - pqy*lx + pqz*lw;

        // rotate rest_d[j] by parent quat: r = d + qw*t + cross(qvec,t), t = 2*cross(qvec,d)
        float dx = rd[3*j+0], dy = rd[3*j+1], dz = rd[3*j+2];
        float tx = 2.0f * (pqy*dz - pqz*dy);
        float ty = 2.0f * (pqz*dx - pqx*dz);
        float tz = 2.0f * (pqx*dy - pqy*dx);
        float rx = dx + pw*tx + (pqy*tz - pqz*ty);
        float ry = dy + pw*ty + (pqz*tx - pqx*tz);
        float rz = dz + pw*tz + (pqx*ty - pqy*tx);

        float L = bl[j];
        gpx[j] = gpx[p] + rx * L;
        gpy[j] = gpy[p] + ry * L;
        gpz[j] = gpz[p] + rz * L;

        // overwrite consumed quat rows with position (rows 4j..4j+2)
        lds[(4*j + 0) * STRIDE + tid] = gpx[j];
        lds[(4*j + 1) * STRIDE + tid] = gpy[j];
        lds[(4*j + 2) * STRIDE + tid] = gpz[j];
    }

    __syncthreads();

    // ---- Cooperative coalesced store: 128 elems * 72 floats = 2304 float4 ----
    {
        float4* dst = (float4*)(out + (size_t)blockBase * 72);
        #pragma unroll
        for (int m = 0; m < 18; ++m) {
            int g = m * BLOCK + tid;      // float4 index within output region [0,2304)
            int t = g / 18;               // element column
            int r = 4 * (g % 18);         // component index 0..68 (multiple of 4)
            float4 v;
            { int rr = r + 0; v.x = lds[(4*(rr/3) + (rr%3)) * STRIDE + t]; }
            { int rr = r + 1; v.y = lds[(4*(rr/3) + (rr%3)) * STRIDE + t]; }
            { int rr = r + 2; v.z = lds[(4*(rr/3) + (rr%3)) * STRIDE + t]; }
            { int rr = r + 3; v.w = lds[(4*(rr/3) + (rr%3)) * STRIDE + t]; }
            dst[g] = v;
        }
    }
}

extern "C" void kernel_launch(void* const* d_in, const int* in_sizes, int n_in,
                              void* d_out, int out_size, void* d_ws, size_t ws_size,
                              hipStream_t stream) {
    const float* root_q = (const float*)d_in[0];
    const float* root_p = (const float*)d_in[1];
    const float* loc_q  = (const float*)d_in[2];
    const float* bones  = (const float*)d_in[3];
    const float* rest_d = (const float*)d_in[4];
    float* out = (float*)d_out;

    dim3 grid(NB / BLOCK);
    dim3 block(BLOCK);
    ForwardKinematics_51342039056994_kernel<<<grid, block, 0, stream>>>(
        root_q, root_p, loc_q, bones, rest_d, out);
}